// Round 16
// baseline (427.471 us; speedup 1.0000x reference)
//
#include <hip/hip_runtime.h>
#include <stdint.h>

#define B_ 2
#define S_ 2048
#define C_ 768
#define H_ 8
#define DH 96
#define CTX 128
#define I_ 3072
#define M_ (B_*S_)
#define N3 (3*C_)

typedef unsigned short u16;
typedef __bf16 bf16x8 __attribute__((ext_vector_type(8)));
typedef float f32x4 __attribute__((ext_vector_type(4)));

__device__ __forceinline__ u16 f2b(float f){
  union { float f; uint32_t u; } v; v.f = f;
  uint32_t r = (v.u + 0x7FFFu + ((v.u >> 16) & 1u)) >> 16;
  return (u16)r;
}
__device__ __forceinline__ float b2f(u16 h){
  union { uint32_t u; float f; } v; v.u = ((uint32_t)h) << 16;
  return v.f;
}
__device__ __forceinline__ void gload_lds16(const void* g, void* l){
  __builtin_amdgcn_global_load_lds((const __attribute__((address_space(1))) void*)g,
                                   (__attribute__((address_space(3))) void*)l, 16, 0, 0);
}
// barrier that orders LDS ops but does NOT drain vmcnt
__device__ __forceinline__ void lgkm_barrier(){
  __builtin_amdgcn_sched_barrier(0);
  asm volatile("s_waitcnt lgkmcnt(0)" ::: "memory");
  __builtin_amdgcn_s_barrier();
  __builtin_amdgcn_sched_barrier(0);
}

__constant__ float INVF[16] = {
  1.0f, 0.5623413251903491f, 0.31622776601683794f, 0.17782794100389228f,
  0.1f, 0.05623413251903491f, 0.03162277660168379f, 0.017782794100389228f,
  0.01f, 0.005623413251903491f, 0.0031622776601683794f, 0.0017782794100389228f,
  0.001f, 0.0005623413251903491f, 0.00031622776601683794f, 0.00017782794100389227f
};

// ---------------- fused weight convert+transpose ----------------
struct WEnt { const float* src; u16* dst; int K; int N; int t0; int map; int rowMul; int rowAdd; };
struct WPack { WEnt e[9]; };

__global__ __launch_bounds__(256) void wconv_all_kernel(WPack p){
  __shared__ float tile[32][33];
  const int t = blockIdx.x;
  int i = 0;
  #pragma unroll
  for(int j=1;j<9;j++) if(t >= p.e[j].t0) i = j;
  const float* __restrict__ Wsrc = p.e[i].src;
  u16* __restrict__ Wt = p.e[i].dst;
  const int K = p.e[i].K, N = p.e[i].N;
  const int mp = p.e[i].map, rM = p.e[i].rowMul, rA = p.e[i].rowAdd;
  const int rel = t - p.e[i].t0;
  const int ntx = N >> 5;
  const int n0 = (rel % ntx) << 5, k0 = (rel / ntx) << 5;
  const int tx = threadIdx.x & 31, ty = threadIdx.x >> 5;
  #pragma unroll
  for(int q=0;q<4;q++)
    tile[ty + q*8][tx] = Wsrc[(size_t)(k0 + ty + q*8) * N + n0 + tx];
  __syncthreads();
  #pragma unroll
  for(int q=0;q<4;q++){
    const int n = n0 + ty + q*8;
    const size_t row = mp ? (size_t)(((n>>5)<<6) + (n&31) + rA) : ((size_t)n*rM + rA);
    Wt[row * K + k0 + tx] = f2b(tile[tx][ty + q*8]);
  }
}

// ---------------- f32 -> bf16 ----------------
__global__ void cvt_kernel(const float* __restrict__ in, u16* __restrict__ out, int n){
  int i = blockIdx.x*256 + threadIdx.x;
  if(i < n) out[i] = f2b(in[i]);
}

// ---------------- LayerNorm over rows of 768, bf16 out ----------------
__global__ __launch_bounds__(256) void ln_kernel(const float* __restrict__ x, const float* __restrict__ g,
    const float* __restrict__ bb, u16* __restrict__ out)
{
  const int row = blockIdx.x;
  const int t = threadIdx.x;
  const float* xr = x + (size_t)row * C_;
  float v0 = xr[t], v1 = xr[t+256], v2 = xr[t+512];
  float s = v0+v1+v2;
  float s2 = v0*v0 + v1*v1 + v2*v2;
  #pragma unroll
  for(int off=32; off>0; off>>=1){ s += __shfl_down(s, off); s2 += __shfl_down(s2, off); }
  __shared__ float red[8];
  const int lane = t & 63, wv = t >> 6;
  if(lane == 0){ red[wv] = s; red[4+wv] = s2; }
  __syncthreads();
  s = red[0]+red[1]+red[2]+red[3];
  s2 = red[4]+red[5]+red[6]+red[7];
  const float mu = s * (1.0f/C_);
  const float inv = rsqrtf(s2*(1.0f/C_) - mu*mu + 1e-5f);
  u16* orow = out + (size_t)row*C_;
  orow[t]     = f2b((v0-mu)*inv*g[t]     + bb[t]);
  orow[t+256] = f2b((v1-mu)*inv*g[t+256] + bb[t+256]);
  orow[t+512] = f2b((v2-mu)*inv*g[t+512] + bb[t+512]);
}

// ---------------- GEMM: 3-buffer pipeline with counted vmcnt. Tile (MI*32) x 128. Split-K z/kz. ----
template<int MI>
__global__ __launch_bounds__(256) void gemm_kernel(
    const u16* __restrict__ A, const u16* __restrict__ Bt,
    u16* __restrict__ Ob, float* __restrict__ Of, const float* __restrict__ resid,
    int Mdim, int Ndim, int Kdim, int Kfull, int kz, int mode, int swiz)
{
  constexpr int BM = MI*32;
  __shared__ __align__(16) u16 As[3][BM*32];
  __shared__ __align__(16) u16 Bs[3][128*32];
  const int tid = threadIdx.x;
  const int lane = tid & 63, w = tid >> 6;
  const int wm = w >> 1, wn = w & 1;
  const int gx = gridDim.x, gy = gridDim.y;
  int m0, n0;
  if(swiz == 2){
    const int lin = blockIdx.y * gx + blockIdx.x;
    const int xcd = lin & 7, c = lin >> 3;
    const int mg = c / 24, r = c - mg*24;
    const int nl = r >> 2, ml = (mg << 2) + (r & 3);
    n0 = (xcd*6 + nl) * 128;
    m0 = ml * BM;
  } else if(swiz == 1){
    int lin = blockIdx.y * gx + blockIdx.x;
    const int nwg = gx * gy;
    lin = (lin & 7) * (nwg >> 3) + (lin >> 3);
    m0 = (lin / gx) * BM;
    n0 = (lin % gx) * 128;
  } else {
    m0 = blockIdx.y * BM;
    n0 = blockIdx.x * 128;
  }
  const size_t zoff = (size_t)blockIdx.z * kz;
  A += zoff; Bt += zoff;
  f32x4 acc[MI][4] = {};
  const int sr = tid >> 2;
  const int sc = (tid & 3) << 3;
  const int l15 = lane & 15, lk = (lane >> 4) << 3;
  const int nsteps = Kdim >> 5;

  auto STAGE = [&](int s){
    const int k0 = s << 5;
    const int buf = s % 3;
    #pragma unroll
    for(int j = 0; j < MI/2; j++)
      gload_lds16(A  + (size_t)(m0 + sr + (j<<6)) * Kfull + k0 + sc, &As[buf][(tid<<3) + (j<<11)]);
    #pragma unroll
    for(int j = 0; j < 2; j++)
      gload_lds16(Bt + (size_t)(n0 + sr + (j<<6)) * Kfull + k0 + sc, &Bs[buf][(tid<<3) + (j<<11)]);
  };
  STAGE(0);
  if(nsteps > 1) STAGE(1);
  __builtin_amdgcn_sched_barrier(0);
  if(nsteps > 1){
    if constexpr(MI == 2) asm volatile("s_waitcnt vmcnt(3)" ::: "memory");
    else                  asm volatile("s_waitcnt vmcnt(4)" ::: "memory");
  } else {
    asm volatile("s_waitcnt vmcnt(0)" ::: "memory");
  }
  asm volatile("s_waitcnt lgkmcnt(0)" ::: "memory");
  __builtin_amdgcn_s_barrier();
  __builtin_amdgcn_sched_barrier(0);

  for(int s = 0; s < nsteps; s++){
    if(s + 2 < nsteps) STAGE(s + 2);
    const int buf = s % 3;
    bf16x8 af[MI], bfr[4];
    #pragma unroll
    for(int i=0;i<MI;i++) af[i]  = *(const bf16x8*)(&As[buf][(wm*(MI*16) + i*16 + l15)*32 + lk]);
    #pragma unroll
    for(int i=0;i<4;i++) bfr[i] = *(const bf16x8*)(&Bs[buf][(wn*64 + i*16 + l15)*32 + lk]);
    #pragma unroll
    for(int mi=0;mi<MI;mi++)
      #pragma unroll
      for(int ni=0;ni<4;ni++)
        acc[mi][ni] = __builtin_amdgcn_mfma_f32_16x16x32_bf16(af[mi], bfr[ni], acc[mi][ni], 0,0,0);
    if(s + 1 < nsteps){
      __builtin_amdgcn_sched_barrier(0);
      if(s + 2 < nsteps){
        if constexpr(MI == 2) asm volatile("s_waitcnt vmcnt(3)" ::: "memory");
        else                  asm volatile("s_waitcnt vmcnt(4)" ::: "memory");
      } else {
        asm volatile("s_waitcnt vmcnt(0)" ::: "memory");
      }
      asm volatile("s_waitcnt lgkmcnt(0)" ::: "memory");
      __builtin_amdgcn_s_barrier();
      __builtin_amdgcn_sched_barrier(0);
    }
  }
  const int rbase = m0 + wm*(MI*16) + ((lane>>4)<<2);
  const int cbase = n0 + wn*64 + l15;
  if(mode == 1){
    #pragma unroll
    for(int mi=0;mi<MI;mi++)
      #pragma unroll
      for(int ni=0;ni<4;ni++)
        #pragma unroll
        for(int r=0;r<4;r++){
          size_t idx = (size_t)(rbase + mi*16 + r) * Ndim + cbase + ni*16;
          Of[idx] = acc[mi][ni][r] + resid[idx];
        }
  } else if(mode == 0){
    #pragma unroll
    for(int mi=0;mi<MI;mi++)
      #pragma unroll
      for(int ni=0;ni<4;ni++)
        #pragma unroll
        for(int r=0;r<4;r++)
          Ob[(size_t)(rbase + mi*16 + r) * Ndim + cbase + ni*16] = f2b(acc[mi][ni][r]);
  } else if(mode == 2){
    const int half = Ndim >> 1;
    const int colb = (n0 + wn*64) >> 1;
    #pragma unroll
    for(int mi=0;mi<MI;mi++)
      #pragma unroll
      for(int ni=0;ni<2;ni++)
        #pragma unroll
        for(int r=0;r<4;r++){
          float g = acc[mi][ni][r];
          float u = acc[mi][ni+2][r];
          Ob[(size_t)(rbase + mi*16 + r) * half + colb + ni*16 + l15] =
              f2b(g / (1.0f + __expf(-g)) * u);
        }
  } else { // mode 4: split-K partial
    float* Oz = Of + (size_t)blockIdx.z * Mdim * Ndim;
    #pragma unroll
    for(int mi=0;mi<MI;mi++)
      #pragma unroll
      for(int ni=0;ni<4;ni++)
        #pragma unroll
        for(int r=0;r<4;r++)
          Oz[(size_t)(rbase + mi*16 + r) * Ndim + cbase + ni*16] = acc[mi][ni][r];
  }
}

// ---------------- split-K combine: out = p0 + p1 + resid (f32x4) ----------------
__global__ void dpcombine_kernel(const float* __restrict__ part, const float* __restrict__ resid,
                                 float* __restrict__ out){
  const int i = blockIdx.x*256 + threadIdx.x;
  f32x4 a = ((const f32x4*)part)[i];
  f32x4 b = ((const f32x4*)(part + (size_t)M_*C_))[i];
  f32x4 r = ((const f32x4*)resid)[i];
  ((f32x4*)out)[i] = a + b + r;
}

// ---------------- split-K combine: out_bf16 = p0 + p1 ----------------
__global__ void skcombine_b16_kernel(const float* __restrict__ part, u16* __restrict__ out){
  const int i = blockIdx.x*256 + threadIdx.x;
  f32x4 a = ((const f32x4*)part)[i];
  f32x4 b = ((const f32x4*)(part + (size_t)M_*C_))[i];
  ushort4 o;
  o.x = f2b(a[0]+b[0]); o.y = f2b(a[1]+b[1]); o.z = f2b(a[2]+b[2]); o.w = f2b(a[3]+b[3]);
  ((ushort4*)out)[i] = o;
}

// ---------------- RoPE in-place on q,k slices of qkv (bf16), 16B vectorized, table inv-freq ----
__global__ void rope_kernel(u16* qkv, const int* hp, const int* wp){
  const int W = wp[0], HH = hp[0];
  int idx = blockIdx.x*256 + threadIdx.x;
  if(idx >= M_*H_*6) return;
  const int c = idx % 6;
  int t1 = idx / 6;
  const int h = t1 & 7;
  const int m = t1 >> 3;
  const int d0 = c*8;
  const int s = m & (S_-1);
  const int xc = s % W;
  const int y  = (s / W) % HH;
  const int tf = s / (W*HH);
  float c1v[8], s1v[8], c2v[8], s2v[8];
  #pragma unroll
  for(int j=0;j<8;j++){
    const int d = d0 + j;
    const float invf = INVF[d & 15];
    const float pos1 = (float)(d < 32 ? xc : y);
    const float pos2 = (float)(d < 16 ? y : tf);
    __sincosf(pos1 * invf, &s1v[j], &c1v[j]);
    __sincosf(pos2 * invf, &s2v[j], &c2v[j]);
  }
  const size_t base = (size_t)m * N3 + h*DH + d0;
  #pragma unroll
  for(int part=0; part<2; part++){
    u16* p = qkv + base + (size_t)part*C_;
    uint4 lo = *(const uint4*)p;
    uint4 hi = *(const uint4*)(p + 48);
    const u16* lw = (const u16*)&lo; const u16* hw = (const u16*)&hi;
    uint4 olo, ohi; u16* ol = (u16*)&olo; u16* oh = (u16*)&ohi;
    #pragma unroll
    for(int j=0;j<8;j++){
      float x1 = b2f(lw[j]), x2 = b2f(hw[j]);
      ol[j] = f2b(x1*c1v[j] - x2*s1v[j]);
      oh[j] = f2b(x2*c2v[j] + x1*s2v[j]);
    }
    *(uint4*)p = olo;
    *(uint4*)(p + 48) = ohi;
  }
}

// ---------------- V transpose ----------------
__global__ __launch_bounds__(256) void vt_kernel(const u16* __restrict__ src, u16* __restrict__ dst,
                                                 int rowStride, int colOff, int seqLen){
  const int bh = blockIdx.y, b = bh >> 3, h = bh & 7;
  const int s0 = blockIdx.x*64;
  __shared__ u16 t[64][DH+8];
  const int tid = threadIdx.x;
  #pragma unroll
  for(int i=0;i<24;i++){
    int e = tid + i*256; int si = e/DH, d = e - si*DH;
    t[si][d] = src[(size_t)(b*seqLen + s0+si)*rowStride + colOff + h*DH + d];
  }
  __syncthreads();
  #pragma unroll
  for(int i=0;i<24;i++){
    int e = tid + i*256; int d = e >> 6, si = e & 63;
    dst[((size_t)bh*DH + d)*seqLen + s0 + si] = t[si][d];
  }
}

// ---------------- Flash attention: KVBLK=128, swapped QK^T per-lane-row softmax, lgkm barriers,
// 2-deep K reg prefetch, setprio on MFMA. mode 0 = cross; mode 1 = self causal (4x128 chunks).
__global__ __launch_bounds__(256,4) void attn_kernel(
    const u16* __restrict__ qp, int qStride, int qOff,
    const u16* __restrict__ kp, int kStride, int kOff,
    const u16* __restrict__ vt,   // (bh, DH, kvLen)
    u16* __restrict__ op,         // (B*S, C) at col h*DH
    u16* __restrict__ part,       // partial slots: 6400 u16 each (O bf16 6144, m f32 64, l f32 64)
    int kvLen, int mode)
{
  __shared__ __align__(16) u16 Ks[128][104];
  __shared__ __align__(16) u16 Plds[4][16][132];
  const int lin = blockIdx.x;
  const int xcd = lin & 7;
  const int i = lin >> 3;
  const int bh = xcd + ((i & 1) << 3);   // 2 (b,h) pairs per XCD -> K/V L2-resident
  int qt, ch, nCh, s;
  if(mode == 0){ s = 0; qt = i >> 1; ch = 0; nCh = 1; }
  else {
    s = i >> 1;                          // 0..79
    if(s < 8){ qt = s; ch = 0; nCh = 1; }
    else if(s < 24){ qt = 8 + ((s-8) >> 1); ch = (s-8) & 1; nCh = 2; }
    else if(s < 48){ int u = s-24; qt = 16 + u/3; ch = u%3; nCh = 3; }
    else { int u = s-48; qt = 24 + (u>>2); ch = u&3; nCh = 4; }
  }
  const int b = bh >> 3, h = bh & 7;
  const int q0 = qt << 6;
  const int nT = mode ? ((qt + 2) >> 1) : (kvLen >> 7);   // 128-kv tiles
  const int tA = mode ? ch*4 : 0;
  const int tB = mode ? min(tA + 4, nT) : nT;
  const int kvA = tA << 7;
  const int tid = threadIdx.x;
  const int lane = tid & 63, w = tid >> 6;
  const int l15 = lane & 15, lg = lane >> 4, lk = lg << 3;
  const int qrow_base = q0 + w*16;
  const float scale = 0.1020620726159658f;  // 96^-0.5

  bf16x8 qf[3];
  {
    const size_t qb = (size_t)(b*S_ + qrow_base + l15) * qStride + qOff + h*DH;
    #pragma unroll
    for(int ks=0;ks<3;ks++) qf[ks] = *(const bf16x8*)(qp + qb + ks*32 + lk);
  }

  // staging: 128x96 K tile = 1536 16B-chunks, 6 per thread
  int krow[6], kcol[6];
  #pragma unroll
  for(int r=0;r<6;r++){
    int c = r*256 + tid;
    krow[r] = c/12; kcol[r] = (c - krow[r]*12)*8;
  }
  const u16* kbase = kp + (size_t)b*kvLen*kStride + kOff + h*DH;
  const u16* vbase = vt + (size_t)bh*DH*kvLen;

  uint4 kreg[6];
  #pragma unroll
  for(int r=0;r<6;r++) kreg[r] = *(const uint4*)(kbase + (size_t)(kvA + krow[r])*kStride + kcol[r]);
  #pragma unroll
  for(int r=0;r<6;r++) *(uint4*)(&Ks[krow[r]][kcol[r]]) = kreg[r];
  if(tA+1 < tB){
    #pragma unroll
    for(int r=0;r<6;r++) kreg[r] = *(const uint4*)(kbase + (size_t)(kvA + 128 + krow[r])*kStride + kcol[r]);
  }
  lgkm_barrier();

  f32x4 oacc[6] = {};
  float mrow = -3e38f, lrow = 0.f;     // per-lane: q-row = qrow_base + l15

  for(int t=tA; t<tB; t++){
    const int kv0 = t << 7;
    // === swapped QK^T: sacc[nt] = S[kv = kv0+nt*16+lg*4+r][q = qrow_base+l15] ===
    f32x4 sacc[8] = {};
    __builtin_amdgcn_s_setprio(1);
    #pragma unroll
    for(int nt=0;nt<8;nt++){
      #pragma unroll
      for(int ks=0;ks<3;ks++){
        bf16x8 kf = *(const bf16x8*)(&Ks[nt*16+l15][ks*32+lk]);
        sacc[nt] = __builtin_amdgcn_mfma_f32_16x16x32_bf16(kf, qf[ks], sacc[nt], 0,0,0);
      }
    }
    __builtin_amdgcn_s_setprio(0);
    // === mask + online softmax, per-lane row ===
    const bool doMask = (mode != 0) && (kv0 + 128 > qrow_base);
    const int myq = qrow_base + l15;
    float mt = -3e38f;
    #pragma unroll
    for(int nt=0;nt<8;nt++)
      #pragma unroll
      for(int r=0;r<4;r++){
        float v = sacc[nt][r] * scale;
        if(doMask && (kv0 + nt*16 + (lg<<2) + r > myq)) v = -3e38f;
        sacc[nt][r] = v;
        mt = fmaxf(mt, v);
      }
    mt = fmaxf(mt, __shfl_xor(mt, 16));
    mt = fmaxf(mt, __shfl_xor(mt, 32));
    const float mn = fmaxf(mrow, mt);
    const float al = __expf(mrow - mn);
    mrow = mn;
    float rs = 0.f;
    #pragma unroll
    for(int nt=0;nt<8;nt++)
      #pragma unroll
      for(int r=0;r<4;r++){
        float pv = __expf(sacc[nt][r] - mn);
        sacc[nt][r] = pv;
        rs += pv;
      }
    rs += __shfl_xor(rs, 16);
    rs += __shfl_xor(rs, 32);
    lrow = lrow*al + rs;
    float alr[4];
    #pragma unroll
    for(int r=0;r<4;r++) alr[r] = __shfl(al, (lg<<2) + r, 16);
    #pragma unroll
    for(int n=0;n<6;n++)
      #pragma unroll
      for(int r=0;r<4;r++) oacc[n][r] *= alr[r];
    // P -> LDS: Plds[w][q=l15][kv], packed b64 per nt
    #pragma unroll
    for(int nt=0;nt<8;nt++){
      uint32_t lo = (uint32_t)f2b(sacc[nt][0]) | ((uint32_t)f2b(sacc[nt][1]) << 16);
      uint32_t hi = (uint32_t)f2b(sacc[nt][2]) | ((uint32_t)f2b(sacc[nt][3]) << 16);
      *(uint2*)(&Plds[w][l15][nt*16 + (lg<<2)]) = make_uint2(lo, hi);
    }
    // === PV over 4 k-slices of 32 kv ===
    #pragma unroll
    for(int kk=0;kk<4;kk++){
      bf16x8 pf = *(const bf16x8*)(&Plds[w][l15][kk*32 + lk]);
      __builtin_amdgcn_s_setprio(1);
      #pragma unroll
      for(int n=0;n<6;n++){
        bf16x8 vf = *(const bf16x8*)(vbase + (size_t)(n*16+l15)*kvLen + kv0 + kk*32 + lk);
        oacc[n] = __builtin_amdgcn_mfma_f32_16x16x32_bf16(pf, vf, oacc[n], 0,0,0);
      }
      __builtin_amdgcn_s_setprio(0);
    }
    lgkm_barrier();                // all waves done reading Ks tile t (K prefetch stays in flight)
    if(t+1 < tB){
      #pragma unroll
      for(int r=0;r<6;r++) *(uint4*)(&Ks[krow[r]][kcol[r]]) = kreg[r];   // commit t+1
      if(t+2 < tB){
        #pragma unroll
        for(int r=0;r<6;r++) kreg[r] = *(const uint4*)(kbase + (size_t)((size_t)(t+2)*128 + krow[r])*kStride + kcol[r]);
      }
      lgkm_barrier();              // Ks commit visible; t+2 loads remain in flight
    }
  }
  // per-output-row l: lane's oacc rows are q = lg*4 + r; fetch lrow from owner lane (l15 = q)
  float lr[4];
  #pragma unroll
  for(int r=0;r<4;r++) lr[r] = __shfl(lrow, (lg<<2) + r, 16);
  if(nCh == 1){
    #pragma unroll
    for(int n=0;n<6;n++)
      #pragma unroll
      for(int r=0;r<4;r++){
        const int qq = qrow_base + (lg<<2) + r;
        op[(size_t)(b*S_ + qq)*C_ + h*DH + n*16 + l15] = f2b(oacc[n][r] / lr[r]);
      }
  } else {
    u16* pb = part + (size_t)(bh*72 + s - 8) * 6400;
    #pragma unroll
    for(int n=0;n<6;n++)
      #pragma unroll
      for(int r=0;r<4;r++)
        pb[(w*16 + (lg<<2) + r)*96 + n*16 + l15] = f2b(oacc[n][r]);
    if(lg == 0){
      float* pm = (float*)(pb + 6144);
      float* pl = (float*)(pb + 6272);
      pm[w*16 + l15] = mrow;
      pl[w*16 + l15] = lrow;
    }
  }
}

// ---------------- combine 2..4 kv-chunk partials -> normalized bf16 output (qt>=8) ----------------
__global__ __launch_bounds__(256) void attn_combine_kernel(const u16* __restrict__ part, u16* __restrict__ op){
  const int blk = blockIdx.x;          // 16*24 = 384
  const int bh = blk / 24;
  const int qt = 8 + blk - bh*24;
  const int b = bh >> 3, h = bh & 7;
  int nCh, s0;
  if(qt < 16){ nCh = 2; s0 = 8 + 2*(qt-8); }
  else if(qt < 24){ nCh = 3; s0 = 24 + 3*(qt-16); }
  else { nCh = 4; s0 = 48 + 4*(qt-24); }
  const u16* pb = part + (size_t)(bh*72 + s0 - 8) * 6400;
  const int q0 = qt << 6;
  for(int k=0;k<24;k++){
    const int e = threadIdx.x + k*256;
    const int row = e / 96, col = e - row*96;
    float Mx = -3e38f;
    for(int c=0;c<nCh;c++)
      Mx = fmaxf(Mx, ((const float*)(pb + c*6400 + 6144))[row]);
    float num = 0.f, den = 0.f;
    for(int c=0;c<nCh;c++){
      const u16* ps = pb + c*6400;
      const float wgt = __expf(((const float*)(ps + 6144))[row] - Mx);
      den += wgt * ((const float*)(ps + 6272))[row];
      num += wgt * b2f(ps[row*96 + col]);
    }
    op[(size_t)(b*S_ + q0 + row)*C_ + h*DH + col] = f2b(num/den);
  }
}

extern "C" void kernel_launch(void* const* d_in, const int* in_sizes, int n_in,
                              void* d_out, int out_size, void* d_ws, size_t ws_size,
                              hipStream_t stream)
{
  (void)in_sizes; (void)n_in; (void)out_size;
  const float* x    = (const float*)d_in[0];
  const float* ctxF = (const float*)d_in[1];
  const float* wqkvF= (const float*)d_in[2];
  const float* waoF = (const float*)d_in[3];
  const float* ln1g = (const float*)d_in[4];
  const float* ln1b = (const float*)d_in[5];
  const float* wqcF = (const float*)d_in[6];
  const float* wkcF = (const float*)d_in[7];
  const float* wvcF = (const float*)d_in[8];
  const float* wcoF = (const float*)d_in[9];
  const float* ln2g = (const float*)d_in[10];
  const float* ln2b = (const float*)d_in[11];
  const float* wgF  = (const float*)d_in[12];
  const float* wuF  = (const float*)d_in[13];
  const float* wdF  = (const float*)d_in[14];
  const float* ln3g = (const float*)d_in[15];
  const float* ln3b = (const float*)d_in[16];
  const int* hgt = (const int*)d_in[17];
  const int* wid = (const int*)d_in[18];
  float* out = (float*)d_out;

  char* base = (char*)d_ws;
  size_t off = 0;
  auto alloc = [&](size_t bytes)->void*{
    void* r = base + off;
    off += (bytes + 255) & ~(size_t)255;
    return r;
  };
  u16* wqkvT = (u16*)alloc((size_t)N3*C_*2);
  u16* waoT  = (u16*)alloc((size_t)C_*C_*2);
  u16* wqcT  = (u16*)alloc((size_t)C_*C_*2);
  u16* wkvcT = (u16*)alloc((size_t)2*C_*C_*2);
  u16* wcoT  = (u16*)alloc((size_t)C_*C_*2);
  u16* wguT  = (u16*)alloc((size_t)2*I_*C_*2);   // per-64-row group: 32 gate cols then 32 up cols
  u16* wdT   = (u16*)alloc((size_t)C_*I_*2);
  u16* ctxb  = (u16*)alloc((size_t)B_*CTX*C_*2);
  u16* xn    = (u16*)alloc((size_t)M_*C_*2);
  u16* gateb = (u16*)alloc((size_t)M_*I_*2);     // silu output (MLP phase)
  float* x1  = (float*)alloc((size_t)M_*C_*4);
  float* x2  = (float*)alloc((size_t)M_*C_*4);
  char* uni  = (char*)alloc((size_t)M_*2*I_*2);  // 50.33 MB transient union
  u16* qkvb = (u16*)uni;                                      // 18.87 MB (self-attn phase)
  u16* vtb  = (u16*)(uni + 18874368);                         //  6.29 MB
  u16* obuf = (u16*)(uni + 18874368 + 1*6291456);             //  6.29 MB
  u16* qcb  = (u16*)(uni + 18874368 + 2*6291456);             //  6.29 MB (cross phase)
  u16* kvcb = (u16*)(uni + 18874368 + 3*6291456);             //  0.79 MB (cross phase)
  u16* vctb = (u16*)(uni + 18874368 + 3*6291456 + 786432);    //  0.39 MB (cross phase)
  u16* part = (u16*)(uni + 18874368 + 2*6291456);             // 14.75 MB (self-attn phase)
  float* dpart = (float*)uni;                                 // 24 MiB split-K partials: [0, 25165824)
                                                              // = exactly up to obuf start; aliases
                                                              // dead qkvb/vtb in each phase it's used
  if(off > ws_size) return;

  dim3 blk(256);
  WPack wp;
  wp.e[0] = { wqkvF, wqkvT,                 C_, N3,   0,    0, 1, 0 };
  wp.e[1] = { waoF,  waoT,                  C_, C_,   1728, 0, 1, 0 };
  wp.e[2] = { wqcF,  wqcT,                  C_, C_,   2304, 0, 1, 0 };
  wp.e[3] = { wkcF,  wkvcT,                 C_, C_,   2880, 0, 1, 0 };
  wp.e[4] = { wvcF,  wkvcT + (size_t)C_*C_, C_, C_,   3456, 0, 1, 0 };
  wp.e[5] = { wcoF,  wcoT,                  C_, C_,   4032, 0, 1, 0 };
  wp.e[6] = { wgF,   wguT,                  C_, I_,   4608, 1, 0, 0 };
  wp.e[7] = { wuF,   wguT,                  C_, I_,   6912, 1, 0, 32 };
  wp.e[8] = { wdF,   wdT,                   I_, C_,   9216, 0, 1, 0 };
  wconv_all_kernel<<<dim3(11520), blk, 0, stream>>>(wp);
  cvt_kernel<<<dim3((B_*CTX*C_+255)/256), blk, 0, stream>>>(ctxF, ctxb, B_*CTX*C_);

  // ---- self attention ----
  ln_kernel<<<dim3(M_), blk, 0, stream>>>(x, ln1g, ln1b, xn);
  gemm_kernel<2><<<dim3(N3/128, M_/64), blk, 0, stream>>>(xn, wqkvT, qkvb, nullptr, nullptr, M_, N3, C_, C_, 0, 0, 1);
  rope_kernel<<<dim3((M_*H_*6+255)/256), blk, 0, stream>>>(qkvb, hgt, wid);
  vt_kernel<<<dim3(S_/64, B_*H_), blk, 0, stream>>>(qkvb, vtb, N3, 2*C_, S_);
  attn_kernel<<<dim3(1280), blk, 0, stream>>>(qkvb, N3, 0, qkvb, N3, C_, vtb, obuf, part, S_, 1);
  attn_combine_kernel<<<dim3(384), blk, 0, stream>>>(part, obuf);
  // attn-out projection: split-K x2 (qkvb/vtb dead; dpart safe) -> x1 = p0+p1+x
  gemm_kernel<2><<<dim3(C_/128, M_/64, 2), blk, 0, stream>>>(obuf, waoT, nullptr, dpart, nullptr, M_, C_, C_/2, C_, C_/2, 4, 1);
  dpcombine_kernel<<<dim3(M_*C_/4/256), blk, 0, stream>>>(dpart, x, x1);

  // ---- cross attention ----
  ln_kernel<<<dim3(M_), blk, 0, stream>>>(x1, ln2g, ln2b, xn);
  // q_c projection: split-K x2 -> qcb (bf16)
  gemm_kernel<2><<<dim3(C_/128, M_/64, 2), blk, 0, stream>>>(xn, wqcT, nullptr, dpart, nullptr, M_, C_, C_/2, C_, C_/2, 4, 1);
  skcombine_b16_kernel<<<dim3(M_*C_/4/256), blk, 0, stream>>>(dpart, qcb);
  gemm_kernel<2><<<dim3(2*C_/128, (B_*CTX)/64), blk, 0, stream>>>(ctxb, wkvcT, kvcb, nullptr, nullptr, B_*CTX, 2*C_, C_, C_, 0, 0, 1);
  vt_kernel<<<dim3(CTX/64, B_*H_), blk, 0, stream>>>(kvcb, vctb, 2*C_, C_, CTX);
  attn_kernel<<<dim3(512), blk, 0, stream>>>(qcb, C_, 0, kvcb, 2*C_, 0, vctb, obuf, nullptr, CTX, 0);
  // cross-out projection: split-K x2 -> x2 = p0+p1+x1
  gemm_kernel<2><<<dim3(C_/128, M_/64, 2), blk, 0, stream>>>(obuf, wcoT, nullptr, dpart, nullptr, M_, C_, C_/2, C_, C_/2, 4, 1);
  dpcombine_kernel<<<dim3(M_*C_/4/256), blk, 0, stream>>>(dpart, x1, x2);

  // ---- MLP ----
  ln_kernel<<<dim3(M_), blk, 0, stream>>>(x2, ln3g, ln3b, xn);
  gemm_kernel<4><<<dim3(2*I_/128, M_/128), blk, 0, stream>>>(xn, wguT, gateb, nullptr, nullptr, M_, 2*I_, C_, C_, 0, 2, 2);
  gemm_kernel<2><<<dim3(C_/128, M_/64, 2), blk, 0, stream>>>(gateb, wdT, nullptr, dpart, nullptr, M_, C_, I_/2, I_, I_/2, 4, 1);
  dpcombine_kernel<<<dim3(M_*C_/4/256), blk, 0, stream>>>(dpart, x2, out);
}

// Round 17
// 413.363 us; speedup vs baseline: 1.0341x; 1.0341x over previous
//
#include <hip/hip_runtime.h>
#include <stdint.h>

#define B_ 2
#define S_ 2048
#define C_ 768
#define H_ 8
#define DH 96
#define CTX 128
#define I_ 3072
#define M_ (B_*S_)
#define N3 (3*C_)

typedef unsigned short u16;
typedef __bf16 bf16x8 __attribute__((ext_vector_type(8)));
typedef float f32x4 __attribute__((ext_vector_type(4)));

__device__ __forceinline__ u16 f2b(float f){
  union { float f; uint32_t u; } v; v.f = f;
  uint32_t r = (v.u + 0x7FFFu + ((v.u >> 16) & 1u)) >> 16;
  return (u16)r;
}
__device__ __forceinline__ float b2f(u16 h){
  union { uint32_t u; float f; } v; v.u = ((uint32_t)h) << 16;
  return v.f;
}
__device__ __forceinline__ void gload_lds16(const void* g, void* l){
  __builtin_amdgcn_global_load_lds((const __attribute__((address_space(1))) void*)g,
                                   (__attribute__((address_space(3))) void*)l, 16, 0, 0);
}
// barrier that orders LDS ops but does NOT drain vmcnt
__device__ __forceinline__ void lgkm_barrier(){
  __builtin_amdgcn_sched_barrier(0);
  asm volatile("s_waitcnt lgkmcnt(0)" ::: "memory");
  __builtin_amdgcn_s_barrier();
  __builtin_amdgcn_sched_barrier(0);
}

__constant__ float INVF[16] = {
  1.0f, 0.5623413251903491f, 0.31622776601683794f, 0.17782794100389228f,
  0.1f, 0.05623413251903491f, 0.03162277660168379f, 0.017782794100389228f,
  0.01f, 0.005623413251903491f, 0.0031622776601683794f, 0.0017782794100389228f,
  0.001f, 0.0005623413251903491f, 0.00031622776601683794f, 0.00017782794100389227f
};

// ---------------- fused weight convert+transpose ----------------
struct WEnt { const float* src; u16* dst; int K; int N; int t0; int map; int rowMul; int rowAdd; };
struct WPack { WEnt e[9]; };

__global__ __launch_bounds__(256) void wconv_all_kernel(WPack p){
  __shared__ float tile[32][33];
  const int t = blockIdx.x;
  int i = 0;
  #pragma unroll
  for(int j=1;j<9;j++) if(t >= p.e[j].t0) i = j;
  const float* __restrict__ Wsrc = p.e[i].src;
  u16* __restrict__ Wt = p.e[i].dst;
  const int K = p.e[i].K, N = p.e[i].N;
  const int mp = p.e[i].map, rM = p.e[i].rowMul, rA = p.e[i].rowAdd;
  const int rel = t - p.e[i].t0;
  const int ntx = N >> 5;
  const int n0 = (rel % ntx) << 5, k0 = (rel / ntx) << 5;
  const int tx = threadIdx.x & 31, ty = threadIdx.x >> 5;
  #pragma unroll
  for(int q=0;q<4;q++)
    tile[ty + q*8][tx] = Wsrc[(size_t)(k0 + ty + q*8) * N + n0 + tx];
  __syncthreads();
  #pragma unroll
  for(int q=0;q<4;q++){
    const int n = n0 + ty + q*8;
    const size_t row = mp ? (size_t)(((n>>5)<<6) + (n&31) + rA) : ((size_t)n*rM + rA);
    Wt[row * K + k0 + tx] = f2b(tile[tx][ty + q*8]);
  }
}

// ---------------- f32 -> bf16 ----------------
__global__ void cvt_kernel(const float* __restrict__ in, u16* __restrict__ out, int n){
  int i = blockIdx.x*256 + threadIdx.x;
  if(i < n) out[i] = f2b(in[i]);
}

// ---------------- LayerNorm over rows of 768, bf16 out ----------------
__global__ __launch_bounds__(256) void ln_kernel(const float* __restrict__ x, const float* __restrict__ g,
    const float* __restrict__ bb, u16* __restrict__ out)
{
  const int row = blockIdx.x;
  const int t = threadIdx.x;
  const float* xr = x + (size_t)row * C_;
  float v0 = xr[t], v1 = xr[t+256], v2 = xr[t+512];
  float s = v0+v1+v2;
  float s2 = v0*v0 + v1*v1 + v2*v2;
  #pragma unroll
  for(int off=32; off>0; off>>=1){ s += __shfl_down(s, off); s2 += __shfl_down(s2, off); }
  __shared__ float red[8];
  const int lane = t & 63, wv = t >> 6;
  if(lane == 0){ red[wv] = s; red[4+wv] = s2; }
  __syncthreads();
  s = red[0]+red[1]+red[2]+red[3];
  s2 = red[4]+red[5]+red[6]+red[7];
  const float mu = s * (1.0f/C_);
  const float inv = rsqrtf(s2*(1.0f/C_) - mu*mu + 1e-5f);
  u16* orow = out + (size_t)row*C_;
  orow[t]     = f2b((v0-mu)*inv*g[t]     + bb[t]);
  orow[t+256] = f2b((v1-mu)*inv*g[t+256] + bb[t+256]);
  orow[t+512] = f2b((v2-mu)*inv*g[t+512] + bb[t+512]);
}

// ---------------- GEMM: 3-buffer pipeline with counted vmcnt. Tile (MI*32) x 128. Split-K z/kz. ----
template<int MI>
__global__ __launch_bounds__(256) void gemm_kernel(
    const u16* __restrict__ A, const u16* __restrict__ Bt,
    u16* __restrict__ Ob, float* __restrict__ Of, const float* __restrict__ resid,
    int Mdim, int Ndim, int Kdim, int Kfull, int kz, int mode, int swiz)
{
  constexpr int BM = MI*32;
  __shared__ __align__(16) u16 As[3][BM*32];
  __shared__ __align__(16) u16 Bs[3][128*32];
  const int tid = threadIdx.x;
  const int lane = tid & 63, w = tid >> 6;
  const int wm = w >> 1, wn = w & 1;
  const int gx = gridDim.x, gy = gridDim.y;
  int m0, n0;
  if(swiz == 2){
    const int lin = blockIdx.y * gx + blockIdx.x;
    const int xcd = lin & 7, c = lin >> 3;
    const int mg = c / 24, r = c - mg*24;
    const int nl = r >> 2, ml = (mg << 2) + (r & 3);
    n0 = (xcd*6 + nl) * 128;
    m0 = ml * BM;
  } else if(swiz == 1){
    int lin = blockIdx.y * gx + blockIdx.x;
    const int nwg = gx * gy;
    lin = (lin & 7) * (nwg >> 3) + (lin >> 3);
    m0 = (lin / gx) * BM;
    n0 = (lin % gx) * 128;
  } else {
    m0 = blockIdx.y * BM;
    n0 = blockIdx.x * 128;
  }
  const size_t zoff = (size_t)blockIdx.z * kz;
  A += zoff; Bt += zoff;
  f32x4 acc[MI][4] = {};
  const int sr = tid >> 2;
  const int sc = (tid & 3) << 3;
  const int l15 = lane & 15, lk = (lane >> 4) << 3;
  const int nsteps = Kdim >> 5;

  auto STAGE = [&](int s){
    const int k0 = s << 5;
    const int buf = s % 3;
    #pragma unroll
    for(int j = 0; j < MI/2; j++)
      gload_lds16(A  + (size_t)(m0 + sr + (j<<6)) * Kfull + k0 + sc, &As[buf][(tid<<3) + (j<<11)]);
    #pragma unroll
    for(int j = 0; j < 2; j++)
      gload_lds16(Bt + (size_t)(n0 + sr + (j<<6)) * Kfull + k0 + sc, &Bs[buf][(tid<<3) + (j<<11)]);
  };
  STAGE(0);
  if(nsteps > 1) STAGE(1);
  __builtin_amdgcn_sched_barrier(0);
  if(nsteps > 1){
    if constexpr(MI == 2) asm volatile("s_waitcnt vmcnt(3)" ::: "memory");
    else                  asm volatile("s_waitcnt vmcnt(4)" ::: "memory");
  } else {
    asm volatile("s_waitcnt vmcnt(0)" ::: "memory");
  }
  asm volatile("s_waitcnt lgkmcnt(0)" ::: "memory");
  __builtin_amdgcn_s_barrier();
  __builtin_amdgcn_sched_barrier(0);

  for(int s = 0; s < nsteps; s++){
    if(s + 2 < nsteps) STAGE(s + 2);
    const int buf = s % 3;
    bf16x8 af[MI], bfr[4];
    #pragma unroll
    for(int i=0;i<MI;i++) af[i]  = *(const bf16x8*)(&As[buf][(wm*(MI*16) + i*16 + l15)*32 + lk]);
    #pragma unroll
    for(int i=0;i<4;i++) bfr[i] = *(const bf16x8*)(&Bs[buf][(wn*64 + i*16 + l15)*32 + lk]);
    #pragma unroll
    for(int mi=0;mi<MI;mi++)
      #pragma unroll
      for(int ni=0;ni<4;ni++)
        acc[mi][ni] = __builtin_amdgcn_mfma_f32_16x16x32_bf16(af[mi], bfr[ni], acc[mi][ni], 0,0,0);
    if(s + 1 < nsteps){
      __builtin_amdgcn_sched_barrier(0);
      if(s + 2 < nsteps){
        if constexpr(MI == 2) asm volatile("s_waitcnt vmcnt(3)" ::: "memory");
        else                  asm volatile("s_waitcnt vmcnt(4)" ::: "memory");
      } else {
        asm volatile("s_waitcnt vmcnt(0)" ::: "memory");
      }
      asm volatile("s_waitcnt lgkmcnt(0)" ::: "memory");
      __builtin_amdgcn_s_barrier();
      __builtin_amdgcn_sched_barrier(0);
    }
  }
  const int rbase = m0 + wm*(MI*16) + ((lane>>4)<<2);
  const int cbase = n0 + wn*64 + l15;
  if(mode == 1){
    #pragma unroll
    for(int mi=0;mi<MI;mi++)
      #pragma unroll
      for(int ni=0;ni<4;ni++)
        #pragma unroll
        for(int r=0;r<4;r++){
          size_t idx = (size_t)(rbase + mi*16 + r) * Ndim + cbase + ni*16;
          Of[idx] = acc[mi][ni][r] + resid[idx];
        }
  } else if(mode == 0){
    #pragma unroll
    for(int mi=0;mi<MI;mi++)
      #pragma unroll
      for(int ni=0;ni<4;ni++)
        #pragma unroll
        for(int r=0;r<4;r++)
          Ob[(size_t)(rbase + mi*16 + r) * Ndim + cbase + ni*16] = f2b(acc[mi][ni][r]);
  } else if(mode == 2){
    const int half = Ndim >> 1;
    const int colb = (n0 + wn*64) >> 1;
    #pragma unroll
    for(int mi=0;mi<MI;mi++)
      #pragma unroll
      for(int ni=0;ni<2;ni++)
        #pragma unroll
        for(int r=0;r<4;r++){
          float g = acc[mi][ni][r];
          float u = acc[mi][ni+2][r];
          Ob[(size_t)(rbase + mi*16 + r) * half + colb + ni*16 + l15] =
              f2b(g / (1.0f + __expf(-g)) * u);
        }
  } else { // mode 4: split-K partial
    float* Oz = Of + (size_t)blockIdx.z * Mdim * Ndim;
    #pragma unroll
    for(int mi=0;mi<MI;mi++)
      #pragma unroll
      for(int ni=0;ni<4;ni++)
        #pragma unroll
        for(int r=0;r<4;r++)
          Oz[(size_t)(rbase + mi*16 + r) * Ndim + cbase + ni*16] = acc[mi][ni][r];
  }
}

// ---------------- split-K combine: out = p0 + p1 + resid (f32x4) ----------------
__global__ void dpcombine_kernel(const float* __restrict__ part, const float* __restrict__ resid,
                                 float* __restrict__ out){
  const int i = blockIdx.x*256 + threadIdx.x;
  f32x4 a = ((const f32x4*)part)[i];
  f32x4 b = ((const f32x4*)(part + (size_t)M_*C_))[i];
  f32x4 r = ((const f32x4*)resid)[i];
  ((f32x4*)out)[i] = a + b + r;
}

// ---------------- RoPE in-place on q,k slices of qkv (bf16), 16B vectorized, table inv-freq ----
__global__ void rope_kernel(u16* qkv, const int* hp, const int* wp){
  const int W = wp[0], HH = hp[0];
  int idx = blockIdx.x*256 + threadIdx.x;
  if(idx >= M_*H_*6) return;
  const int c = idx % 6;
  int t1 = idx / 6;
  const int h = t1 & 7;
  const int m = t1 >> 3;
  const int d0 = c*8;
  const int s = m & (S_-1);
  const int xc = s % W;
  const int y  = (s / W) % HH;
  const int tf = s / (W*HH);
  float c1v[8], s1v[8], c2v[8], s2v[8];
  #pragma unroll
  for(int j=0;j<8;j++){
    const int d = d0 + j;
    const float invf = INVF[d & 15];
    const float pos1 = (float)(d < 32 ? xc : y);
    const float pos2 = (float)(d < 16 ? y : tf);
    __sincosf(pos1 * invf, &s1v[j], &c1v[j]);
    __sincosf(pos2 * invf, &s2v[j], &c2v[j]);
  }
  const size_t base = (size_t)m * N3 + h*DH + d0;
  #pragma unroll
  for(int part=0; part<2; part++){
    u16* p = qkv + base + (size_t)part*C_;
    uint4 lo = *(const uint4*)p;
    uint4 hi = *(const uint4*)(p + 48);
    const u16* lw = (const u16*)&lo; const u16* hw = (const u16*)&hi;
    uint4 olo, ohi; u16* ol = (u16*)&olo; u16* oh = (u16*)&ohi;
    #pragma unroll
    for(int j=0;j<8;j++){
      float x1 = b2f(lw[j]), x2 = b2f(hw[j]);
      ol[j] = f2b(x1*c1v[j] - x2*s1v[j]);
      oh[j] = f2b(x2*c2v[j] + x1*s2v[j]);
    }
    *(uint4*)p = olo;
    *(uint4*)(p + 48) = ohi;
  }
}

// ---------------- V transpose ----------------
__global__ __launch_bounds__(256) void vt_kernel(const u16* __restrict__ src, u16* __restrict__ dst,
                                                 int rowStride, int colOff, int seqLen){
  const int bh = blockIdx.y, b = bh >> 3, h = bh & 7;
  const int s0 = blockIdx.x*64;
  __shared__ u16 t[64][DH+8];
  const int tid = threadIdx.x;
  #pragma unroll
  for(int i=0;i<24;i++){
    int e = tid + i*256; int si = e/DH, d = e - si*DH;
    t[si][d] = src[(size_t)(b*seqLen + s0+si)*rowStride + colOff + h*DH + d];
  }
  __syncthreads();
  #pragma unroll
  for(int i=0;i<24;i++){
    int e = tid + i*256; int d = e >> 6, si = e & 63;
    dst[((size_t)bh*DH + d)*seqLen + s0 + si] = t[si][d];
  }
}

// ---------------- Flash attention: KVBLK=128, swapped QK^T per-lane-row softmax, lgkm barriers,
// 2-deep K reg prefetch, setprio on MFMA. mode 0 = cross; mode 1 = self causal (4x128 chunks).
__global__ __launch_bounds__(256,4) void attn_kernel(
    const u16* __restrict__ qp, int qStride, int qOff,
    const u16* __restrict__ kp, int kStride, int kOff,
    const u16* __restrict__ vt,   // (bh, DH, kvLen)
    u16* __restrict__ op,         // (B*S, C) at col h*DH
    u16* __restrict__ part,       // partial slots: 6400 u16 each (O bf16 6144, m f32 64, l f32 64)
    int kvLen, int mode)
{
  __shared__ __align__(16) u16 Ks[128][104];
  __shared__ __align__(16) u16 Plds[4][16][132];
  const int lin = blockIdx.x;
  const int xcd = lin & 7;
  const int i = lin >> 3;
  const int bh = xcd + ((i & 1) << 3);   // 2 (b,h) pairs per XCD -> K/V L2-resident
  int qt, ch, nCh, s;
  if(mode == 0){ s = 0; qt = i >> 1; ch = 0; nCh = 1; }
  else {
    s = i >> 1;                          // 0..79
    if(s < 8){ qt = s; ch = 0; nCh = 1; }
    else if(s < 24){ qt = 8 + ((s-8) >> 1); ch = (s-8) & 1; nCh = 2; }
    else if(s < 48){ int u = s-24; qt = 16 + u/3; ch = u%3; nCh = 3; }
    else { int u = s-48; qt = 24 + (u>>2); ch = u&3; nCh = 4; }
  }
  const int b = bh >> 3, h = bh & 7;
  const int q0 = qt << 6;
  const int nT = mode ? ((qt + 2) >> 1) : (kvLen >> 7);   // 128-kv tiles
  const int tA = mode ? ch*4 : 0;
  const int tB = mode ? min(tA + 4, nT) : nT;
  const int kvA = tA << 7;
  const int tid = threadIdx.x;
  const int lane = tid & 63, w = tid >> 6;
  const int l15 = lane & 15, lg = lane >> 4, lk = lg << 3;
  const int qrow_base = q0 + w*16;
  const float scale = 0.1020620726159658f;  // 96^-0.5

  bf16x8 qf[3];
  {
    const size_t qb = (size_t)(b*S_ + qrow_base + l15) * qStride + qOff + h*DH;
    #pragma unroll
    for(int ks=0;ks<3;ks++) qf[ks] = *(const bf16x8*)(qp + qb + ks*32 + lk);
  }

  // staging: 128x96 K tile = 1536 16B-chunks, 6 per thread
  int krow[6], kcol[6];
  #pragma unroll
  for(int r=0;r<6;r++){
    int c = r*256 + tid;
    krow[r] = c/12; kcol[r] = (c - krow[r]*12)*8;
  }
  const u16* kbase = kp + (size_t)b*kvLen*kStride + kOff + h*DH;
  const u16* vbase = vt + (size_t)bh*DH*kvLen;

  uint4 kreg[6];
  #pragma unroll
  for(int r=0;r<6;r++) kreg[r] = *(const uint4*)(kbase + (size_t)(kvA + krow[r])*kStride + kcol[r]);
  #pragma unroll
  for(int r=0;r<6;r++) *(uint4*)(&Ks[krow[r]][kcol[r]]) = kreg[r];
  if(tA+1 < tB){
    #pragma unroll
    for(int r=0;r<6;r++) kreg[r] = *(const uint4*)(kbase + (size_t)(kvA + 128 + krow[r])*kStride + kcol[r]);
  }
  lgkm_barrier();

  f32x4 oacc[6] = {};
  float mrow = -3e38f, lrow = 0.f;     // per-lane: q-row = qrow_base + l15

  for(int t=tA; t<tB; t++){
    const int kv0 = t << 7;
    // === swapped QK^T: sacc[nt] = S[kv = kv0+nt*16+lg*4+r][q = qrow_base+l15] ===
    f32x4 sacc[8] = {};
    __builtin_amdgcn_s_setprio(1);
    #pragma unroll
    for(int nt=0;nt<8;nt++){
      #pragma unroll
      for(int ks=0;ks<3;ks++){
        bf16x8 kf = *(const bf16x8*)(&Ks[nt*16+l15][ks*32+lk]);
        sacc[nt] = __builtin_amdgcn_mfma_f32_16x16x32_bf16(kf, qf[ks], sacc[nt], 0,0,0);
      }
    }
    __builtin_amdgcn_s_setprio(0);
    // === mask + online softmax, per-lane row ===
    const bool doMask = (mode != 0) && (kv0 + 128 > qrow_base);
    const int myq = qrow_base + l15;
    float mt = -3e38f;
    #pragma unroll
    for(int nt=0;nt<8;nt++)
      #pragma unroll
      for(int r=0;r<4;r++){
        float v = sacc[nt][r] * scale;
        if(doMask && (kv0 + nt*16 + (lg<<2) + r > myq)) v = -3e38f;
        sacc[nt][r] = v;
        mt = fmaxf(mt, v);
      }
    mt = fmaxf(mt, __shfl_xor(mt, 16));
    mt = fmaxf(mt, __shfl_xor(mt, 32));
    const float mn = fmaxf(mrow, mt);
    const float al = __expf(mrow - mn);
    mrow = mn;
    float rs = 0.f;
    #pragma unroll
    for(int nt=0;nt<8;nt++)
      #pragma unroll
      for(int r=0;r<4;r++){
        float pv = __expf(sacc[nt][r] - mn);
        sacc[nt][r] = pv;
        rs += pv;
      }
    rs += __shfl_xor(rs, 16);
    rs += __shfl_xor(rs, 32);
    lrow = lrow*al + rs;
    float alr[4];
    #pragma unroll
    for(int r=0;r<4;r++) alr[r] = __shfl(al, (lg<<2) + r, 16);
    #pragma unroll
    for(int n=0;n<6;n++)
      #pragma unroll
      for(int r=0;r<4;r++) oacc[n][r] *= alr[r];
    // P -> LDS: Plds[w][q=l15][kv], packed b64 per nt
    #pragma unroll
    for(int nt=0;nt<8;nt++){
      uint32_t lo = (uint32_t)f2b(sacc[nt][0]) | ((uint32_t)f2b(sacc[nt][1]) << 16);
      uint32_t hi = (uint32_t)f2b(sacc[nt][2]) | ((uint32_t)f2b(sacc[nt][3]) << 16);
      *(uint2*)(&Plds[w][l15][nt*16 + (lg<<2)]) = make_uint2(lo, hi);
    }
    // === PV over 4 k-slices of 32 kv ===
    #pragma unroll
    for(int kk=0;kk<4;kk++){
      bf16x8 pf = *(const bf16x8*)(&Plds[w][l15][kk*32 + lk]);
      __builtin_amdgcn_s_setprio(1);
      #pragma unroll
      for(int n=0;n<6;n++){
        bf16x8 vf = *(const bf16x8*)(vbase + (size_t)(n*16+l15)*kvLen + kv0 + kk*32 + lk);
        oacc[n] = __builtin_amdgcn_mfma_f32_16x16x32_bf16(pf, vf, oacc[n], 0,0,0);
      }
      __builtin_amdgcn_s_setprio(0);
    }
    lgkm_barrier();                // all waves done reading Ks tile t (K prefetch stays in flight)
    if(t+1 < tB){
      #pragma unroll
      for(int r=0;r<6;r++) *(uint4*)(&Ks[krow[r]][kcol[r]]) = kreg[r];   // commit t+1
      if(t+2 < tB){
        #pragma unroll
        for(int r=0;r<6;r++) kreg[r] = *(const uint4*)(kbase + (size_t)((size_t)(t+2)*128 + krow[r])*kStride + kcol[r]);
      }
      lgkm_barrier();              // Ks commit visible; t+2 loads remain in flight
    }
  }
  // per-output-row l: lane's oacc rows are q = lg*4 + r; fetch lrow from owner lane (l15 = q)
  float lr[4];
  #pragma unroll
  for(int r=0;r<4;r++) lr[r] = __shfl(lrow, (lg<<2) + r, 16);
  if(nCh == 1){
    #pragma unroll
    for(int n=0;n<6;n++)
      #pragma unroll
      for(int r=0;r<4;r++){
        const int qq = qrow_base + (lg<<2) + r;
        op[(size_t)(b*S_ + qq)*C_ + h*DH + n*16 + l15] = f2b(oacc[n][r] / lr[r]);
      }
  } else {
    u16* pb = part + (size_t)(bh*72 + s - 8) * 6400;
    #pragma unroll
    for(int n=0;n<6;n++)
      #pragma unroll
      for(int r=0;r<4;r++)
        pb[(w*16 + (lg<<2) + r)*96 + n*16 + l15] = f2b(oacc[n][r]);
    if(lg == 0){
      float* pm = (float*)(pb + 6144);
      float* pl = (float*)(pb + 6272);
      pm[w*16 + l15] = mrow;
      pl[w*16 + l15] = lrow;
    }
  }
}

// ---------------- combine 2..4 kv-chunk partials -> normalized bf16 output (qt>=8) ----------------
__global__ __launch_bounds__(256) void attn_combine_kernel(const u16* __restrict__ part, u16* __restrict__ op){
  const int blk = blockIdx.x;          // 16*24 = 384
  const int bh = blk / 24;
  const int qt = 8 + blk - bh*24;
  const int b = bh >> 3, h = bh & 7;
  int nCh, s0;
  if(qt < 16){ nCh = 2; s0 = 8 + 2*(qt-8); }
  else if(qt < 24){ nCh = 3; s0 = 24 + 3*(qt-16); }
  else { nCh = 4; s0 = 48 + 4*(qt-24); }
  const u16* pb = part + (size_t)(bh*72 + s0 - 8) * 6400;
  const int q0 = qt << 6;
  for(int k=0;k<24;k++){
    const int e = threadIdx.x + k*256;
    const int row = e / 96, col = e - row*96;
    float Mx = -3e38f;
    for(int c=0;c<nCh;c++)
      Mx = fmaxf(Mx, ((const float*)(pb + c*6400 + 6144))[row]);
    float num = 0.f, den = 0.f;
    for(int c=0;c<nCh;c++){
      const u16* ps = pb + c*6400;
      const float wgt = __expf(((const float*)(ps + 6144))[row] - Mx);
      den += wgt * ((const float*)(ps + 6272))[row];
      num += wgt * b2f(ps[row*96 + col]);
    }
    op[(size_t)(b*S_ + q0 + row)*C_ + h*DH + col] = f2b(num/den);
  }
}

extern "C" void kernel_launch(void* const* d_in, const int* in_sizes, int n_in,
                              void* d_out, int out_size, void* d_ws, size_t ws_size,
                              hipStream_t stream)
{
  (void)in_sizes; (void)n_in; (void)out_size;
  const float* x    = (const float*)d_in[0];
  const float* ctxF = (const float*)d_in[1];
  const float* wqkvF= (const float*)d_in[2];
  const float* waoF = (const float*)d_in[3];
  const float* ln1g = (const float*)d_in[4];
  const float* ln1b = (const float*)d_in[5];
  const float* wqcF = (const float*)d_in[6];
  const float* wkcF = (const float*)d_in[7];
  const float* wvcF = (const float*)d_in[8];
  const float* wcoF = (const float*)d_in[9];
  const float* ln2g = (const float*)d_in[10];
  const float* ln2b = (const float*)d_in[11];
  const float* wgF  = (const float*)d_in[12];
  const float* wuF  = (const float*)d_in[13];
  const float* wdF  = (const float*)d_in[14];
  const float* ln3g = (const float*)d_in[15];
  const float* ln3b = (const float*)d_in[16];
  const int* hgt = (const int*)d_in[17];
  const int* wid = (const int*)d_in[18];
  float* out = (float*)d_out;

  char* base = (char*)d_ws;
  size_t off = 0;
  auto alloc = [&](size_t bytes)->void*{
    void* r = base + off;
    off += (bytes + 255) & ~(size_t)255;
    return r;
  };
  u16* wqkvT = (u16*)alloc((size_t)N3*C_*2);
  u16* waoT  = (u16*)alloc((size_t)C_*C_*2);
  u16* wqcT  = (u16*)alloc((size_t)C_*C_*2);
  u16* wkvcT = (u16*)alloc((size_t)2*C_*C_*2);
  u16* wcoT  = (u16*)alloc((size_t)C_*C_*2);
  u16* wguT  = (u16*)alloc((size_t)2*I_*C_*2);   // per-64-row group: 32 gate cols then 32 up cols
  u16* wdT   = (u16*)alloc((size_t)C_*I_*2);
  u16* ctxb  = (u16*)alloc((size_t)B_*CTX*C_*2);
  u16* xn    = (u16*)alloc((size_t)M_*C_*2);
  u16* gateb = (u16*)alloc((size_t)M_*I_*2);     // silu output (MLP phase)
  float* x1  = (float*)alloc((size_t)M_*C_*4);
  float* x2  = (float*)alloc((size_t)M_*C_*4);
  char* uni  = (char*)alloc((size_t)M_*2*I_*2);  // 50.33 MB transient union
  u16* qkvb = (u16*)uni;                                      // 18.87 MB (self-attn phase)
  u16* vtb  = (u16*)(uni + 18874368);                         //  6.29 MB
  u16* obuf = (u16*)(uni + 18874368 + 1*6291456);             //  6.29 MB
  u16* qcb  = (u16*)(uni + 18874368 + 2*6291456);             //  6.29 MB (cross phase)
  u16* kvcb = (u16*)(uni + 18874368 + 3*6291456);             //  0.79 MB (cross phase)
  u16* vctb = (u16*)(uni + 18874368 + 3*6291456 + 786432);    //  0.39 MB (cross phase)
  u16* part = (u16*)(uni + 18874368 + 2*6291456);             // 14.75 MB (self-attn phase)
  float* dpart = (float*)uni;                                 // 25.2 MB split-K partials (MLP phase)
  if(off > ws_size) return;

  dim3 blk(256);
  WPack wp;
  wp.e[0] = { wqkvF, wqkvT,                 C_, N3,   0,    0, 1, 0 };
  wp.e[1] = { waoF,  waoT,                  C_, C_,   1728, 0, 1, 0 };
  wp.e[2] = { wqcF,  wqcT,                  C_, C_,   2304, 0, 1, 0 };
  wp.e[3] = { wkcF,  wkvcT,                 C_, C_,   2880, 0, 1, 0 };
  wp.e[4] = { wvcF,  wkvcT + (size_t)C_*C_, C_, C_,   3456, 0, 1, 0 };
  wp.e[5] = { wcoF,  wcoT,                  C_, C_,   4032, 0, 1, 0 };
  wp.e[6] = { wgF,   wguT,                  C_, I_,   4608, 1, 0, 0 };
  wp.e[7] = { wuF,   wguT,                  C_, I_,   6912, 1, 0, 32 };
  wp.e[8] = { wdF,   wdT,                   I_, C_,   9216, 0, 1, 0 };
  wconv_all_kernel<<<dim3(11520), blk, 0, stream>>>(wp);
  cvt_kernel<<<dim3((B_*CTX*C_+255)/256), blk, 0, stream>>>(ctxF, ctxb, B_*CTX*C_);

  // ---- self attention ----
  ln_kernel<<<dim3(M_), blk, 0, stream>>>(x, ln1g, ln1b, xn);
  gemm_kernel<2><<<dim3(N3/128, M_/64), blk, 0, stream>>>(xn, wqkvT, qkvb, nullptr, nullptr, M_, N3, C_, C_, 0, 0, 1);
  rope_kernel<<<dim3((M_*H_*6+255)/256), blk, 0, stream>>>(qkvb, hgt, wid);
  vt_kernel<<<dim3(S_/64, B_*H_), blk, 0, stream>>>(qkvb, vtb, N3, 2*C_, S_);
  attn_kernel<<<dim3(1280), blk, 0, stream>>>(qkvb, N3, 0, qkvb, N3, C_, vtb, obuf, part, S_, 1);
  attn_combine_kernel<<<dim3(384), blk, 0, stream>>>(part, obuf);
  gemm_kernel<2><<<dim3(C_/128, M_/64), blk, 0, stream>>>(obuf, waoT, nullptr, x1, x, M_, C_, C_, C_, 0, 1, 1);

  // ---- cross attention ----
  ln_kernel<<<dim3(M_), blk, 0, stream>>>(x1, ln2g, ln2b, xn);
  gemm_kernel<2><<<dim3(C_/128, M_/64), blk, 0, stream>>>(xn, wqcT, qcb, nullptr, nullptr, M_, C_, C_, C_, 0, 0, 1);
  gemm_kernel<2><<<dim3(2*C_/128, (B_*CTX)/64), blk, 0, stream>>>(ctxb, wkvcT, kvcb, nullptr, nullptr, B_*CTX, 2*C_, C_, C_, 0, 0, 1);
  vt_kernel<<<dim3(CTX/64, B_*H_), blk, 0, stream>>>(kvcb, vctb, 2*C_, C_, CTX);
  attn_kernel<<<dim3(512), blk, 0, stream>>>(qcb, C_, 0, kvcb, 2*C_, 0, vctb, obuf, nullptr, CTX, 0);
  gemm_kernel<2><<<dim3(C_/128, M_/64), blk, 0, stream>>>(obuf, wcoT, nullptr, x2, x1, M_, C_, C_, C_, 0, 1, 1);

  // ---- MLP ----
  ln_kernel<<<dim3(M_), blk, 0, stream>>>(x2, ln3g, ln3b, xn);
  gemm_kernel<4><<<dim3(2*I_/128, M_/128), blk, 0, stream>>>(xn, wguT, gateb, nullptr, nullptr, M_, 2*I_, C_, C_, 0, 2, 2);
  gemm_kernel<2><<<dim3(C_/128, M_/64, 2), blk, 0, stream>>>(gateb, wdT, nullptr, dpart, nullptr, M_, C_, I_/2, I_, I_/2, 4, 1);
  dpcombine_kernel<<<dim3(M_*C_/4/256), blk, 0, stream>>>(dpart, x2, out);
}